// Round 4
// baseline (254.013 us; speedup 1.0000x reference)
//
#include <hip/hip_runtime.h>

// ============================================================================
// MultiHeadCrossAttention on MI355X (gfx950) — round 12
//   B=2, SQ=SK=2048, H=16, D=64, EMB=CTX=INNER=1024, fp32 in/out.
//
// 4 dispatches:
//   1. cvt6: all fp32->bf16 conversions
//   2. gemm_qkv: 128x128 tiles (m97 shape), XOR-swizzled LDS,
//      q (softmax scale folded), k (+fused LN), vT (key-permuted cols)
//   3. flash2 v8: 8-wave blocks, 4-way K-split (32-key tiles), 64 q/wave,
//      16 waves/CU (4/SIMD) for latency hiding; cvtpk pack; zero-hoist;
//      no setprio. 4-way epilogue combine through LDS.
//   4. gemm_out: 128x64 tiles (512 blocks = 2/CU), wave-tile 64x32
// ============================================================================

typedef __attribute__((ext_vector_type(8)))  short bf16x8;
typedef __attribute__((ext_vector_type(4)))  short bf16x4;
typedef __attribute__((ext_vector_type(4)))  float f32x4;
typedef __attribute__((ext_vector_type(16))) float f32x16;
typedef __attribute__((ext_vector_type(4)))  unsigned int u32x4;

#define SM_SCALE 0.18033688f   // 0.125 * log2(e), folded into q at LN

typedef __attribute__((address_space(1))) const void cg_void;
typedef __attribute__((address_space(3))) void lds_void_t;

__device__ __forceinline__ void gl_lds16(const void* g, void* l){
  __builtin_amdgcn_global_load_lds((cg_void*)g, (lds_void_t*)l, 16, 0, 0);
}

__device__ __forceinline__ short f2b(float f){
  unsigned int u;
  __builtin_memcpy(&u, &f, 4);
  u += 0x7fffu + ((u >> 16) & 1u);   // round-to-nearest-even
  return (short)(u >> 16);
}

// packed bf16 convert: d.lo16 = bf16(a), d.hi16 = bf16(b), RNE
__device__ __forceinline__ unsigned int cvtpk(float a, float b){
  unsigned int r;
  asm("v_cvt_pk_bf16_f32 %0, %1, %2" : "=v"(r) : "v"(a), "v"(b));
  return r;
}

// ---------------------------------------------------------------------------
// Fused fp32 -> bf16 convert of all six inputs (12M elems, 4 per thread).
// ---------------------------------------------------------------------------
__global__ __launch_bounds__(256) void cvt6_kernel(
    const float* __restrict__ emb, const float* __restrict__ ctx,
    const float* __restrict__ Wq, const float* __restrict__ Wk,
    const float* __restrict__ Wv, const float* __restrict__ Wu,
    short* __restrict__ o_emb, short* __restrict__ o_ctx,
    short* __restrict__ o_wq, short* __restrict__ o_wk,
    short* __restrict__ o_wv, short* __restrict__ o_wu)
{
  const long M1 = 1024L * 1024L, M4 = 4L * M1;
  long e = ((long)blockIdx.x * 256 + threadIdx.x) * 4;
  if (e >= 12L * M1) return;
  const float* src; short* dst; long off;
  if      (e <     M4)      { src = emb; dst = o_emb; off = e;           }
  else if (e < 2 * M4)      { src = ctx; dst = o_ctx; off = e - M4;      }
  else if (e < 2 * M4 + M1) { src = Wq;  dst = o_wq;  off = e - 2 * M4;  }
  else if (e < 2 * M4 + 2*M1){src = Wk;  dst = o_wk;  off = e - 2*M4 - M1;}
  else if (e < 2 * M4 + 3*M1){src = Wv;  dst = o_wv;  off = e - 2*M4 - 2*M1;}
  else                      { src = Wu;  dst = o_wu;  off = e - 2*M4 - 3*M1;}
  f32x4 v = *(const f32x4*)(src + off);
  bf16x4 o;
  o[0] = f2b(v[0]); o[1] = f2b(v[1]); o[2] = f2b(v[2]); o[3] = f2b(v[3]);
  *(bf16x4*)(dst + off) = o;
}

// ---------------------------------------------------------------------------
// Fused QKV projections. Grid (256, 3); blockIdx.y = task.
//   task 0: q = (emb@Wq^T -> LN)*SM_SCALE   (bm fastest, x&31)
//   task 1: k = ctx@Wk^T + LN               (bm fastest)
//   task 2: vT = Wv@ctx^T, key-permuted cols (bn fastest, x&31)
// 128x128 tile (m97 shape), BK=64, 4 waves in 2x2, each 64x64 (4x4 MFMA
// 16x16x32). Wave N-span = 64 = one head chunk -> LN stays wave-local.
// 32 KB LDS, 768 blocks = 3 blocks/CU = 12 waves/CU.
// ---------------------------------------------------------------------------
__global__ __launch_bounds__(256, 3) void gemm_qkv_kernel(
    const short* __restrict__ embh, const short* __restrict__ ctxh,
    const short* __restrict__ Wqh, const short* __restrict__ Wkh,
    const short* __restrict__ Wvh,
    short* __restrict__ qo, short* __restrict__ ko, short* __restrict__ vto,
    const float* __restrict__ qw, const float* __restrict__ qb,
    const float* __restrict__ kw, const float* __restrict__ kb)
{
  const int K = 1024;
  __shared__ short As[128 * 64];   // 16 KB
  __shared__ short Bs[128 * 64];   // 16 KB
  const int tid  = threadIdx.x;
  const int wave = tid >> 6, lane = tid & 63;
  const int quad = lane >> 4, r16 = lane & 15;
  const int wm = (wave >> 1) * 64, wn = (wave & 1) * 64;

  const int task = blockIdx.y;
  int bn, bm, N;
  const short *A, *B;
  if (task == 2){
    bn = (blockIdx.x & 31) * 128; bm = (blockIdx.x >> 5) * 128; N = 4096;
    A = Wvh; B = ctxh;
  } else {
    bm = (blockIdx.x & 31) * 128; bn = (blockIdx.x >> 5) * 128; N = 1024;
    A = task ? ctxh : embh; B = task ? Wkh : Wqh;
  }

  f32x4 acc[4][4];
#pragma unroll
  for (int i = 0; i < 4; i++)
#pragma unroll
    for (int j = 0; j < 4; j++)
      acc[i][j] = (f32x4){0.f, 0.f, 0.f, 0.f};

  const int sr7 = (lane >> 3) & 7;
  const size_t arow = (size_t)(bm + wave * 8 + (lane >> 3)) * K
                      + (((lane & 7) ^ sr7) * 8);
  const size_t brow = (size_t)(bn + wave * 8 + (lane >> 3)) * K
                      + (((lane & 7) ^ sr7) * 8);
  const int sw = ((quad ^ (r16 & 7)) << 3);

  for (int k0 = 0; k0 < K; k0 += 64){
#pragma unroll
    for (int i = 0; i < 4; i++)
      gl_lds16(A + arow + (size_t)32 * i * K + k0, &As[wave * 512 + i * 2048]);
#pragma unroll
    for (int i = 0; i < 4; i++)
      gl_lds16(B + brow + (size_t)32 * i * K + k0, &Bs[wave * 512 + i * 2048]);
    __syncthreads();
#pragma unroll
    for (int kk = 0; kk < 2; kk++){
      const int off = sw ^ (kk << 5);
      bf16x8 af[4], bq[4];
#pragma unroll
      for (int i = 0; i < 4; i++)
        af[i] = *(const bf16x8*)(&As[(wm + i*16 + r16) * 64 + off]);
#pragma unroll
      for (int j = 0; j < 4; j++)
        bq[j] = *(const bf16x8*)(&Bs[(wn + j*16 + r16) * 64 + off]);
#pragma unroll
      for (int i = 0; i < 4; i++)
#pragma unroll
        for (int j = 0; j < 4; j++)
          acc[i][j] = __builtin_amdgcn_mfma_f32_16x16x32_bf16(af[i], bq[j], acc[i][j], 0, 0, 0);
    }
    __syncthreads();
  }

  if (task < 2){
    short* Ch = task ? ko : qo;
    const float* lw = task ? kw : qw;
    const float* lb = task ? kb : qb;
    const float post = task ? 1.0f : SM_SCALE;   // fold softmax scale into q
    float wv[4], bv[4];
#pragma unroll
    for (int j = 0; j < 4; j++){
      wv[j] = lw[j*16 + r16] * post;
      bv[j] = lb[j*16 + r16] * post;
    }
#pragma unroll
    for (int i = 0; i < 4; i++){
#pragma unroll
      for (int t = 0; t < 4; t++){
        float a[4];
#pragma unroll
        for (int j = 0; j < 4; j++) a[j] = acc[i][j][t];
        float s = a[0] + a[1] + a[2] + a[3];
        s += __shfl_xor(s, 1); s += __shfl_xor(s, 2);
        s += __shfl_xor(s, 4); s += __shfl_xor(s, 8);
        const float mu = s * 0.015625f;
        float d[4], sq = 0.f;
#pragma unroll
        for (int j = 0; j < 4; j++){ d[j] = a[j] - mu; sq += d[j]*d[j]; }
        sq += __shfl_xor(sq, 1); sq += __shfl_xor(sq, 2);
        sq += __shfl_xor(sq, 4); sq += __shfl_xor(sq, 8);
        const float si = rsqrtf(sq * 0.015625f + 1e-5f);
        const size_t row = (size_t)(bm + wm + i*16 + quad*4 + t);
#pragma unroll
        for (int j = 0; j < 4; j++)
          Ch[row * 1024 + (bn + wn + j*16 + r16)] = f2b(d[j] * si * wv[j] + bv[j]);
      }
    }
  } else {
#pragma unroll
    for (int i = 0; i < 4; i++){
#pragma unroll
      for (int j = 0; j < 4; j++){
        // permute token index within its 32-group into PV fragment order
        const int p = (r16 & 3) | ((j & 1) << 2) | (((r16 >> 2) & 1) << 3)
                      | (((r16 >> 3) & 1) << 4);
        const int col = ((bn + wn + j*16 + r16) & ~31) | p;
#pragma unroll
        for (int t = 0; t < 4; t++){
          const size_t row = (size_t)(bm + wm + i*16 + quad*4 + t);
          vto[row * (size_t)N + col] = f2b(acc[i][j][t]);
        }
      }
    }
  }
}

// ---------------------------------------------------------------------------
// out = ao @ Wu^T + bu. M=4096, N=K=1024, fp32 out.
// 128x64 tile, 256 threads, 4 waves 2x2 each 64x32 (4x2 MFMA) -> AI 21.3
// FLOP/LDS-byte (vs 16 at 64x64). 24 KB LDS, 512 blocks = 2/CU.
// XOR-swizzled LDS. Grid (32, 16): bm fastest (same-B blocks share XCD).
// ---------------------------------------------------------------------------
__global__ __launch_bounds__(256, 3) void gemm_out_kernel(
    const short* __restrict__ A, const short* __restrict__ B,
    float* __restrict__ Cf, const float* __restrict__ bias)
{
  const int K = 1024, N = 1024;
  __shared__ short As[128 * 64];   // 16 KB
  __shared__ short Bs[64 * 64];    //  8 KB
  const int tid  = threadIdx.x;
  const int wave = tid >> 6, lane = tid & 63;
  const int quad = lane >> 4, r16 = lane & 15;
  const int wm = (wave >> 1) * 64, wn = (wave & 1) * 32;
  const int bm = blockIdx.x * 128, bn = blockIdx.y * 64;

  f32x4 acc[4][2];
#pragma unroll
  for (int i = 0; i < 4; i++)
#pragma unroll
    for (int j = 0; j < 2; j++)
      acc[i][j] = (f32x4){0.f, 0.f, 0.f, 0.f};

  const int sr7 = (lane >> 3) & 7;
  const size_t arow = (size_t)(bm + wave * 8 + (lane >> 3)) * K
                      + (((lane & 7) ^ sr7) * 8);
  const size_t brow = (size_t)(bn + wave * 8 + (lane >> 3)) * K
                      + (((lane & 7) ^ sr7) * 8);
  const int sw = ((quad ^ (r16 & 7)) << 3);

  for (int k0 = 0; k0 < K; k0 += 64){
#pragma unroll
    for (int i = 0; i < 4; i++)
      gl_lds16(A + arow + (size_t)32 * i * K + k0, &As[wave * 512 + i * 2048]);
#pragma unroll
    for (int i = 0; i < 2; i++)
      gl_lds16(B + brow + (size_t)32 * i * K + k0, &Bs[wave * 512 + i * 2048]);
    __syncthreads();
#pragma unroll
    for (int kk = 0; kk < 2; kk++){
      const int off = sw ^ (kk << 5);
      bf16x8 af[4], bq[2];
#pragma unroll
      for (int i = 0; i < 4; i++)
        af[i] = *(const bf16x8*)(&As[(wm + i*16 + r16) * 64 + off]);
#pragma unroll
      for (int j = 0; j < 2; j++)
        bq[j] = *(const bf16x8*)(&Bs[(wn + j*16 + r16) * 64 + off]);
#pragma unroll
      for (int i = 0; i < 4; i++)
#pragma unroll
        for (int j = 0; j < 2; j++)
          acc[i][j] = __builtin_amdgcn_mfma_f32_16x16x32_bf16(af[i], bq[j], acc[i][j], 0, 0, 0);
    }
    __syncthreads();
  }

#pragma unroll
  for (int i = 0; i < 4; i++){
#pragma unroll
    for (int j = 0; j < 2; j++){
      const int col = bn + wn + j*16 + r16;
#pragma unroll
      for (int t = 0; t < 4; t++){
        const size_t row = (size_t)(bm + wm + i*16 + quad*4 + t);
        Cf[row * N + col] = acc[i][j][t] + bias[col];
      }
    }
  }
}

// ---------------------------------------------------------------------------
// MFMA flash attention v8 — 8 waves, 4-way K-split, 64 q-rows per wave.
//   Grid (16 h, 16 qb, 2 b) = 512 blocks, 512 threads -> 2 blocks/CU,
//   16 waves/CU = 4 waves/SIMD (2x v7's latency hiding).
//   wave = ks4*2 + wg; ks4 handles key tiles kt = 4i+ks4 (32 keys each);
//   both wg waves of a ksplit share its K/V LDS buffers (each stages half).
//   Per iter per wave: 4 kf reads, 8 S-MFMA (2 chains), 32 exp2 + cvtpk,
//   4 vf reads, 8 PV-MFMA. LDS 64 KB (8 bufs x 4KB x {K,V}).
//   Epilogue: 4-way combine through LDS (52 KB scratch, stride-33).
// ---------------------------------------------------------------------------
__global__ __launch_bounds__(512, 4) void flash2_kernel(
    const short* __restrict__ Q, const short* __restrict__ K,
    const short* __restrict__ Vt, short* __restrict__ O)
{
  __shared__ __align__(16) long long smem8[8192];   // 64 KB
  short* Ks  = (short*)smem8;        // 8 bufs x 2048 shorts: [ks4*2+buf]
  short* Vts = Ks + 16384;           // 8 bufs x 2048 shorts
  float* scr = (float*)smem8;        // epilogue reuse

  const int tid = threadIdx.x;
  const int wave = tid >> 6, lane = tid & 63;
  const int ks4 = wave >> 1, wg = wave & 1;
  const int hh = lane >> 5, q5 = lane & 31;
  const int h = blockIdx.x, qb = blockIdx.y, b = blockIdx.z;
  const int q0 = qb * 128 + wg * 64;

  const size_t kbase = ((size_t)b * 2048) * 1024 + (size_t)h * 64;
  const size_t vbase = ((size_t)h * 64) * 4096 + (size_t)b * 2048;

  // Q B-frags for both q-groups (pre-scaled by SM_SCALE at LN)
  bf16x8 qf[2][4];
#pragma unroll
  for (int qg = 0; qg < 2; qg++){
    const size_t qrow = ((size_t)b * 2048 + q0 + qg * 32 + q5) * 1024 + (size_t)h * 64;
#pragma unroll
    for (int c = 0; c < 4; c++)
      qf[qg][c] = *(const bf16x8*)(Q + qrow + c * 16 + hh * 8);
  }

  f32x16 oacc[2][2];   // [qg][mt]
#pragma unroll
  for (int t = 0; t < 16; t++){
    oacc[0][0][t] = 0.f; oacc[0][1][t] = 0.f;
    oacc[1][0][t] = 0.f; oacc[1][1][t] = 0.f;
  }
  float lacc[2] = {0.f, 0.f};

  // loop-invariant zero C-operand for the S-chain head
  f32x16 zero16;
#pragma unroll
  for (int t = 0; t < 16; t++) zero16[t] = 0.f;

  // staging lane geometry
  const int srow  = lane >> 3;                    // K: row within 8-row group
  const int kcsrc = ((lane & 7) ^ srow) * 8;      // K: swizzled source chunk
  const int vrow  = lane >> 2;                    // V: row within 16-row group
  const int vcsrc = ((lane & 3) ^ (vrow & 3)) * 8;// V: swizzled source chunk

#define STAGE(bufi, kt)                                                          \
  {                                                                              \
    const short* ks = K + kbase + (size_t)((kt) * 32 + wg * 16 + srow) * 1024 + kcsrc; \
    const short* vs = Vt + vbase + (size_t)(wg * 32 + vrow) * 4096 + (kt) * 32 + vcsrc; \
    short* kd = Ks  + (ks4 * 2 + (bufi)) * 2048 + wg * 1024;                     \
    short* vd = Vts + (ks4 * 2 + (bufi)) * 2048 + wg * 1024;                     \
    gl_lds16(ks,             kd);                                                \
    gl_lds16(ks +  8 * 1024, kd + 512);                                          \
    gl_lds16(vs,             vd);                                                \
    gl_lds16(vs + 16 * 4096, vd + 512);                                          \
  }

  STAGE(0, ks4)

  for (int i = 0; i < 16; i++){
    const int buf = i & 1;
    __syncthreads();                         // staging(buf) drained; buf^1 free
    if (i + 1 < 16) STAGE(buf ^ 1, 4 * (i + 1) + ks4)

    const short* kb_l = Ks  + (ks4 * 2 + buf) * 2048;
    const short* vb_l = Vts + (ks4 * 2 + buf) * 2048;

    // ---- 4 kf reads (q-independent, shared by both q-groups) ----
    bf16x8 kf[4];
#pragma unroll
    for (int c = 0; c < 4; c++)
      kf[c] = *(const bf16x8*)(&kb_l[q5 * 64 + (((2*c + hh) ^ (q5 & 7)) << 3)]);

    // ---- S^T = K·Q^T: 2 independent 4-deep MFMA chains ----
    f32x16 sacc[2];   // [qg]
    sacc[0] = __builtin_amdgcn_mfma_f32_32x32x16_bf16(kf[0], qf[0][0], zero16, 0, 0, 0);
    sacc[1] = __builtin_amdgcn_mfma_f32_32x32x16_bf16(kf[0], qf[1][0], zero16, 0, 0, 0);
#pragma unroll
    for (int c = 1; c < 4; c++){
      sacc[0] = __builtin_amdgcn_mfma_f32_32x32x16_bf16(kf[c], qf[0][c], sacc[0], 0, 0, 0);
      sacc[1] = __builtin_amdgcn_mfma_f32_32x32x16_bf16(kf[c], qf[1][c], sacc[1], 0, 0, 0);
    }

    // ---- P = exp2(S^T); pack via v_cvt_pk_bf16_f32; l via VALU trees ----
    bf16x8 pf[2][2];   // [qg][c]
#pragma unroll
    for (int qg = 0; qg < 2; qg++){
      float e[16];
      float pp[4] = {0.f, 0.f, 0.f, 0.f};
#pragma unroll
      for (int t = 0; t < 16; t++){
        e[t] = __builtin_amdgcn_exp2f(sacc[qg][t]);
        pp[t & 3] += e[t];
      }
      lacc[qg] += (pp[0] + pp[1]) + (pp[2] + pp[3]);
#pragma unroll
      for (int c = 0; c < 2; c++){
        u32x4 tmp;
        tmp[0] = cvtpk(e[4*c + 0],     e[4*c + 1]);
        tmp[1] = cvtpk(e[4*c + 2],     e[4*c + 3]);
        tmp[2] = cvtpk(e[8 + 4*c + 0], e[8 + 4*c + 1]);
        tmp[3] = cvtpk(e[8 + 4*c + 2], e[8 + 4*c + 3]);
        __builtin_memcpy(&pf[qg][c], &tmp, 16);
      }
    }

    // ---- O^T += V^T·P^T : vf read once, consumed by both q-groups ----
#pragma unroll
    for (int c = 0; c < 2; c++){
#pragma unroll
      for (int mt = 0; mt < 2; mt++){
        const int d = mt * 32 + q5;
        bf16x8 vf = *(const bf16x8*)(&vb_l[d * 32 + (((2*c + hh) ^ (d & 3)) << 3)]);
        oacc[0][mt] = __builtin_amdgcn_mfma_f32_32x32x16_bf16(vf, pf[0][c], oacc[0][mt], 0, 0, 0);
        oacc[1][mt] = __builtin_amdgcn_mfma_f32_32x32x16_bf16(vf, pf[1][c], oacc[1][mt], 0, 0, 0);
      }
    }
  }

  // ---- 4-way combine through LDS, then store O[q][d] = O^T / l ----
  const int widx = wg * 64 + lane;           // 0..127
  __syncthreads();                           // all buffer reads done
#pragma unroll
  for (int qg = 0; qg < 2; qg++){
    const float lh = lacc[qg] + __shfl_xor(lacc[qg], 32);
    if (ks4 != 0){
      float* base = scr + ((ks4 - 1) * 128 + widx) * 33;
#pragma unroll
      for (int t = 0; t < 16; t++){ base[t] = oacc[qg][0][t]; base[16 + t] = oacc[qg][1][t]; }
      scr[12672 + (ks4 - 1) * 128 + widx] = lh;
    }
    __syncthreads();
    if (ks4 == 0){
      float ob[32];
#pragma unroll
      for (int t = 0; t < 16; t++){ ob[t] = oacc[qg][0][t]; ob[16 + t] = oacc[qg][1][t]; }
      float lsum = lh;
#pragma unroll
      for (int w = 0; w < 3; w++){
        const float* base = scr + (w * 128 + widx) * 33;
#pragma unroll
        for (int t = 0; t < 32; t++) ob[t] += base[t];
        lsum += scr[12672 + w * 128 + widx];
      }
      const float linv = 1.0f / lsum;
      const size_t orow = ((size_t)b * 2048 + q0 + qg * 32 + q5) * 1024 + (size_t)h * 64;
#pragma unroll
      for (int mt = 0; mt < 2; mt++){
#pragma unroll
        for (int g = 0; g < 4; g++){
          bf16x4 o4;
#pragma unroll
          for (int u = 0; u < 4; u++)
            o4[u] = f2b(ob[mt*16 + g*4 + u] * linv);
          *(bf16x4*)(O + orow + mt*32 + g*8 + 4*hh) = o4;
        }
      }
    }
    __syncthreads();
  }
}
#undef STAGE

// ---------------------------------------------------------------------------
extern "C" void kernel_launch(void* const* d_in, const int* in_sizes, int n_in,
                              void* d_out, int out_size, void* d_ws, size_t ws_size,
                              hipStream_t stream) {
  const float* emb  = (const float*)d_in[0];
  const float* ctx  = (const float*)d_in[1];
  const float* Wq   = (const float*)d_in[2];
  const float* Wk   = (const float*)d_in[3];
  const float* Wv   = (const float*)d_in[4];
  const float* Wu   = (const float*)d_in[5];
  const float* bu   = (const float*)d_in[6];
  const float* qn_w = (const float*)d_in[7];
  const float* qn_b = (const float*)d_in[8];
  const float* kn_w = (const float*)d_in[9];
  const float* kn_b = (const float*)d_in[10];
  float* out = (float*)d_out;

  const size_t BIG = (size_t)4096 * 1024;
  const size_t WSZ = (size_t)1024 * 1024;
  short* ws   = (short*)d_ws;
  short* embh = ws;
  short* ctxh = embh + BIG;
  short* Wqh  = ctxh + BIG;
  short* Wkh  = Wqh + WSZ;
  short* Wvh  = Wkh + WSZ;
  short* Wuh  = Wvh + WSZ;
  short* qh   = Wuh + WSZ;
  short* kh   = qh + BIG;
  short* vth  = kh + BIG;    // V^T [inner][token], key-permuted columns
  short* aoh  = vth + BIG;

  cvt6_kernel<<<12288, 256, 0, stream>>>(emb, ctx, Wq, Wk, Wv, Wu,
                                         embh, ctxh, Wqh, Wkh, Wvh, Wuh);

  gemm_qkv_kernel<<<dim3(256, 3), 256, 0, stream>>>(
      embh, ctxh, Wqh, Wkh, Wvh, qh, kh, vth,
      qn_w, qn_b, kn_w, kn_b);

  flash2_kernel<<<dim3(16, 16, 2), 512, 0, stream>>>(qh, kh, vth, aoh);

  gemm_out_kernel<<<dim3(32, 16), 256, 0, stream>>>(aoh, Wuh, out, bu);
}

// Round 5
// 196.114 us; speedup vs baseline: 1.2952x; 1.2952x over previous
//
#include <hip/hip_runtime.h>

// ============================================================================
// MultiHeadCrossAttention on MI355X (gfx950) — round 13
//   B=2, SQ=SK=2048, H=16, D=64, EMB=CTX=INNER=1024, fp32 in/out.
//
// 4 dispatches:
//   1. cvt6: all fp32->bf16 conversions
//   2. gemm_qkv: 128x128 tiles (m97 shape), XOR-swizzled LDS,
//      q (softmax scale folded), k (+fused LN), vT (key-permuted cols)
//   3. flash2 v6 (RESTORED round-10 best): 4-wave blocks, 2-way K-split,
//      64 q-rows per wave, kf/vf shared across 2 q-groups, VALU l-sum
//   4. gemm_out: 128x64 tiles (512 blocks), wave-tile 64x32 (AI 21.3)
// ============================================================================

typedef __attribute__((ext_vector_type(8)))  short bf16x8;
typedef __attribute__((ext_vector_type(4)))  short bf16x4;
typedef __attribute__((ext_vector_type(4)))  float f32x4;
typedef __attribute__((ext_vector_type(16))) float f32x16;
typedef __attribute__((ext_vector_type(4)))  unsigned int u32x4;

#define SM_SCALE 0.18033688f   // 0.125 * log2(e), folded into q at LN

typedef __attribute__((address_space(1))) const void cg_void;
typedef __attribute__((address_space(3))) void lds_void_t;

__device__ __forceinline__ void gl_lds16(const void* g, void* l){
  __builtin_amdgcn_global_load_lds((cg_void*)g, (lds_void_t*)l, 16, 0, 0);
}

__device__ __forceinline__ short f2b(float f){
  unsigned int u;
  __builtin_memcpy(&u, &f, 4);
  u += 0x7fffu + ((u >> 16) & 1u);   // round-to-nearest-even
  return (short)(u >> 16);
}

// ---------------------------------------------------------------------------
// Fused fp32 -> bf16 convert of all six inputs (12M elems, 4 per thread).
// ---------------------------------------------------------------------------
__global__ __launch_bounds__(256) void cvt6_kernel(
    const float* __restrict__ emb, const float* __restrict__ ctx,
    const float* __restrict__ Wq, const float* __restrict__ Wk,
    const float* __restrict__ Wv, const float* __restrict__ Wu,
    short* __restrict__ o_emb, short* __restrict__ o_ctx,
    short* __restrict__ o_wq, short* __restrict__ o_wk,
    short* __restrict__ o_wv, short* __restrict__ o_wu)
{
  const long M1 = 1024L * 1024L, M4 = 4L * M1;
  long e = ((long)blockIdx.x * 256 + threadIdx.x) * 4;
  if (e >= 12L * M1) return;
  const float* src; short* dst; long off;
  if      (e <     M4)      { src = emb; dst = o_emb; off = e;           }
  else if (e < 2 * M4)      { src = ctx; dst = o_ctx; off = e - M4;      }
  else if (e < 2 * M4 + M1) { src = Wq;  dst = o_wq;  off = e - 2 * M4;  }
  else if (e < 2 * M4 + 2*M1){src = Wk;  dst = o_wk;  off = e - 2*M4 - M1;}
  else if (e < 2 * M4 + 3*M1){src = Wv;  dst = o_wv;  off = e - 2*M4 - 2*M1;}
  else                      { src = Wu;  dst = o_wu;  off = e - 2*M4 - 3*M1;}
  f32x4 v = *(const f32x4*)(src + off);
  bf16x4 o;
  o[0] = f2b(v[0]); o[1] = f2b(v[1]); o[2] = f2b(v[2]); o[3] = f2b(v[3]);
  *(bf16x4*)(dst + off) = o;
}

// ---------------------------------------------------------------------------
// Fused QKV projections. Grid (256, 3); blockIdx.y = task.
//   task 0: q = (emb@Wq^T -> LN)*SM_SCALE   (bm fastest, x&31)
//   task 1: k = ctx@Wk^T + LN               (bm fastest)
//   task 2: vT = Wv@ctx^T, key-permuted cols (bn fastest, x&31)
// 128x128 tile (m97 shape), BK=64, 4 waves in 2x2, each 64x64 (4x4 MFMA
// 16x16x32). Wave N-span = 64 = one head chunk -> LN stays wave-local.
// 32 KB LDS, 768 blocks = 3 blocks/CU = 12 waves/CU.
// ---------------------------------------------------------------------------
__global__ __launch_bounds__(256, 3) void gemm_qkv_kernel(
    const short* __restrict__ embh, const short* __restrict__ ctxh,
    const short* __restrict__ Wqh, const short* __restrict__ Wkh,
    const short* __restrict__ Wvh,
    short* __restrict__ qo, short* __restrict__ ko, short* __restrict__ vto,
    const float* __restrict__ qw, const float* __restrict__ qb,
    const float* __restrict__ kw, const float* __restrict__ kb)
{
  const int K = 1024;
  __shared__ short As[128 * 64];   // 16 KB
  __shared__ short Bs[128 * 64];   // 16 KB
  const int tid  = threadIdx.x;
  const int wave = tid >> 6, lane = tid & 63;
  const int quad = lane >> 4, r16 = lane & 15;
  const int wm = (wave >> 1) * 64, wn = (wave & 1) * 64;

  const int task = blockIdx.y;
  int bn, bm, N;
  const short *A, *B;
  if (task == 2){
    bn = (blockIdx.x & 31) * 128; bm = (blockIdx.x >> 5) * 128; N = 4096;
    A = Wvh; B = ctxh;
  } else {
    bm = (blockIdx.x & 31) * 128; bn = (blockIdx.x >> 5) * 128; N = 1024;
    A = task ? ctxh : embh; B = task ? Wkh : Wqh;
  }

  f32x4 acc[4][4];
#pragma unroll
  for (int i = 0; i < 4; i++)
#pragma unroll
    for (int j = 0; j < 4; j++)
      acc[i][j] = (f32x4){0.f, 0.f, 0.f, 0.f};

  const int sr7 = (lane >> 3) & 7;
  const size_t arow = (size_t)(bm + wave * 8 + (lane >> 3)) * K
                      + (((lane & 7) ^ sr7) * 8);
  const size_t brow = (size_t)(bn + wave * 8 + (lane >> 3)) * K
                      + (((lane & 7) ^ sr7) * 8);
  const int sw = ((quad ^ (r16 & 7)) << 3);

  for (int k0 = 0; k0 < K; k0 += 64){
#pragma unroll
    for (int i = 0; i < 4; i++)
      gl_lds16(A + arow + (size_t)32 * i * K + k0, &As[wave * 512 + i * 2048]);
#pragma unroll
    for (int i = 0; i < 4; i++)
      gl_lds16(B + brow + (size_t)32 * i * K + k0, &Bs[wave * 512 + i * 2048]);
    __syncthreads();
#pragma unroll
    for (int kk = 0; kk < 2; kk++){
      const int off = sw ^ (kk << 5);
      bf16x8 af[4], bq[4];
#pragma unroll
      for (int i = 0; i < 4; i++)
        af[i] = *(const bf16x8*)(&As[(wm + i*16 + r16) * 64 + off]);
#pragma unroll
      for (int j = 0; j < 4; j++)
        bq[j] = *(const bf16x8*)(&Bs[(wn + j*16 + r16) * 64 + off]);
#pragma unroll
      for (int i = 0; i < 4; i++)
#pragma unroll
        for (int j = 0; j < 4; j++)
          acc[i][j] = __builtin_amdgcn_mfma_f32_16x16x32_bf16(af[i], bq[j], acc[i][j], 0, 0, 0);
    }
    __syncthreads();
  }

  if (task < 2){
    short* Ch = task ? ko : qo;
    const float* lw = task ? kw : qw;
    const float* lb = task ? kb : qb;
    const float post = task ? 1.0f : SM_SCALE;   // fold softmax scale into q
    float wv[4], bv[4];
#pragma unroll
    for (int j = 0; j < 4; j++){
      wv[j] = lw[j*16 + r16] * post;
      bv[j] = lb[j*16 + r16] * post;
    }
#pragma unroll
    for (int i = 0; i < 4; i++){
#pragma unroll
      for (int t = 0; t < 4; t++){
        float a[4];
#pragma unroll
        for (int j = 0; j < 4; j++) a[j] = acc[i][j][t];
        float s = a[0] + a[1] + a[2] + a[3];
        s += __shfl_xor(s, 1); s += __shfl_xor(s, 2);
        s += __shfl_xor(s, 4); s += __shfl_xor(s, 8);
        const float mu = s * 0.015625f;
        float d[4], sq = 0.f;
#pragma unroll
        for (int j = 0; j < 4; j++){ d[j] = a[j] - mu; sq += d[j]*d[j]; }
        sq += __shfl_xor(sq, 1); sq += __shfl_xor(sq, 2);
        sq += __shfl_xor(sq, 4); sq += __shfl_xor(sq, 8);
        const float si = rsqrtf(sq * 0.015625f + 1e-5f);
        const size_t row = (size_t)(bm + wm + i*16 + quad*4 + t);
#pragma unroll
        for (int j = 0; j < 4; j++)
          Ch[row * 1024 + (bn + wn + j*16 + r16)] = f2b(d[j] * si * wv[j] + bv[j]);
      }
    }
  } else {
#pragma unroll
    for (int i = 0; i < 4; i++){
#pragma unroll
      for (int j = 0; j < 4; j++){
        // permute token index within its 32-group into PV fragment order
        const int p = (r16 & 3) | ((j & 1) << 2) | (((r16 >> 2) & 1) << 3)
                      | (((r16 >> 3) & 1) << 4);
        const int col = ((bn + wn + j*16 + r16) & ~31) | p;
#pragma unroll
        for (int t = 0; t < 4; t++){
          const size_t row = (size_t)(bm + wm + i*16 + quad*4 + t);
          vto[row * (size_t)N + col] = f2b(acc[i][j][t]);
        }
      }
    }
  }
}

// ---------------------------------------------------------------------------
// out = ao @ Wu^T + bu. M=4096, N=K=1024, fp32 out.
// 128x64 tile, 256 threads, 4 waves 2x2 each 64x32 (4x2 MFMA) -> AI 21.3
// FLOP/LDS-byte (vs 16 at 64x64). 24 KB LDS, 512 blocks = 2/CU.
// XOR-swizzled LDS. Grid (32, 16): bm fastest (same-B blocks share XCD).
// ---------------------------------------------------------------------------
__global__ __launch_bounds__(256, 3) void gemm_out_kernel(
    const short* __restrict__ A, const short* __restrict__ B,
    float* __restrict__ Cf, const float* __restrict__ bias)
{
  const int K = 1024, N = 1024;
  __shared__ short As[128 * 64];   // 16 KB
  __shared__ short Bs[64 * 64];    //  8 KB
  const int tid  = threadIdx.x;
  const int wave = tid >> 6, lane = tid & 63;
  const int quad = lane >> 4, r16 = lane & 15;
  const int wm = (wave >> 1) * 64, wn = (wave & 1) * 32;
  const int bm = blockIdx.x * 128, bn = blockIdx.y * 64;

  f32x4 acc[4][2];
#pragma unroll
  for (int i = 0; i < 4; i++)
#pragma unroll
    for (int j = 0; j < 2; j++)
      acc[i][j] = (f32x4){0.f, 0.f, 0.f, 0.f};

  const int sr7 = (lane >> 3) & 7;
  const size_t arow = (size_t)(bm + wave * 8 + (lane >> 3)) * K
                      + (((lane & 7) ^ sr7) * 8);
  const size_t brow = (size_t)(bn + wave * 8 + (lane >> 3)) * K
                      + (((lane & 7) ^ sr7) * 8);
  const int sw = ((quad ^ (r16 & 7)) << 3);

  for (int k0 = 0; k0 < K; k0 += 64){
#pragma unroll
    for (int i = 0; i < 4; i++)
      gl_lds16(A + arow + (size_t)32 * i * K + k0, &As[wave * 512 + i * 2048]);
#pragma unroll
    for (int i = 0; i < 2; i++)
      gl_lds16(B + brow + (size_t)32 * i * K + k0, &Bs[wave * 512 + i * 2048]);
    __syncthreads();
#pragma unroll
    for (int kk = 0; kk < 2; kk++){
      const int off = sw ^ (kk << 5);
      bf16x8 af[4], bq[2];
#pragma unroll
      for (int i = 0; i < 4; i++)
        af[i] = *(const bf16x8*)(&As[(wm + i*16 + r16) * 64 + off]);
#pragma unroll
      for (int j = 0; j < 2; j++)
        bq[j] = *(const bf16x8*)(&Bs[(wn + j*16 + r16) * 64 + off]);
#pragma unroll
      for (int i = 0; i < 4; i++)
#pragma unroll
        for (int j = 0; j < 2; j++)
          acc[i][j] = __builtin_amdgcn_mfma_f32_16x16x32_bf16(af[i], bq[j], acc[i][j], 0, 0, 0);
    }
    __syncthreads();
  }

#pragma unroll
  for (int i = 0; i < 4; i++){
#pragma unroll
    for (int j = 0; j < 2; j++){
      const int col = bn + wn + j*16 + r16;
#pragma unroll
      for (int t = 0; t < 4; t++){
        const size_t row = (size_t)(bm + wm + i*16 + quad*4 + t);
        Cf[row * N + col] = acc[i][j][t] + bias[col];
      }
    }
  }
}

// ---------------------------------------------------------------------------
// MFMA flash attention v6 (RESTORED) — 4 waves, 2-way K-split, 64 q/wave.
//   Grid (16 h, 16 qb, 2 b): h innermost -> per-XCD K/V L2 reuse.
//   wave = half*2 + wg; each wg owns 64 q (two 32-row groups qg=0,1).
//   kf/vf LDS fragments are q-independent -> read ONCE, used by both qg.
//   l via VALU partial trees. 2 blocks/CU (64 KB LDS), 8 waves/CU.
//   Per iter: hoist 8 kf reads; 16 S-MFMAs (4 indep chains); exp2+pack
//   (bit-add + v_perm); 16 PV MFMAs (vf read once, both qg consume).
// ---------------------------------------------------------------------------
__global__ __launch_bounds__(256, 2) void flash2_kernel(
    const short* __restrict__ Q, const short* __restrict__ K,
    const short* __restrict__ Vt, short* __restrict__ O)
{
  __shared__ __align__(16) long long smem8[8192];   // 64 KB
  short* Ks  = (short*)smem8;        // 4 bufs x 4096 shorts: [half*2+buf]
  short* Vts = Ks + 16384;
  float* scr = (float*)smem8;        // epilogue reuse

  const int tid = threadIdx.x;
  const int wave = tid >> 6, lane = tid & 63;
  const int half = wave >> 1, wg = wave & 1;
  const int hh = lane >> 5, q5 = lane & 31;
  const int h = blockIdx.x, qb = blockIdx.y, b = blockIdx.z;
  const int q0 = qb * 128 + wg * 64;

  const size_t kbase = ((size_t)b * 2048) * 1024 + (size_t)h * 64;
  const size_t vbase = ((size_t)h * 64) * 4096 + (size_t)b * 2048;

  // Q B-frags for both q-groups (pre-scaled by SM_SCALE at LN)
  bf16x8 qf[2][4];
#pragma unroll
  for (int qg = 0; qg < 2; qg++){
    const size_t qrow = ((size_t)b * 2048 + q0 + qg * 32 + q5) * 1024 + (size_t)h * 64;
#pragma unroll
    for (int c = 0; c < 4; c++)
      qf[qg][c] = *(const bf16x8*)(Q + qrow + c * 16 + hh * 8);
  }

  f32x16 oacc[2][2];   // [qg][mt]
#pragma unroll
  for (int t = 0; t < 16; t++){
    oacc[0][0][t] = 0.f; oacc[0][1][t] = 0.f;
    oacc[1][0][t] = 0.f; oacc[1][1][t] = 0.f;
  }
  float lacc[2] = {0.f, 0.f};

  const int srow = lane >> 3;
  const int csrc = ((lane & 7) ^ srow) * 8;
  const int wr0 = wg * 32;

#define STAGE(bufi, kt)                                                         \
  {                                                                             \
    const short* ks = K + kbase + (size_t)((kt) * 64 + wr0 + srow) * 1024 + csrc; \
    const short* vs = Vt + vbase + (size_t)(wr0 + srow) * 4096 + (kt) * 64 + csrc; \
    short* kd = Ks  + (half * 2 + (bufi)) * 4096 + wr0 * 64;                    \
    short* vd = Vts + (half * 2 + (bufi)) * 4096 + wr0 * 64;                    \
    gl_lds16(ks,             kd);                                               \
    gl_lds16(ks +  8 * 1024, kd + 512);                                         \
    gl_lds16(ks + 16 * 1024, kd + 1024);                                        \
    gl_lds16(ks + 24 * 1024, kd + 1536);                                        \
    gl_lds16(vs,             vd);                                               \
    gl_lds16(vs +  8 * 4096, vd + 512);                                         \
    gl_lds16(vs + 16 * 4096, vd + 1024);                                        \
    gl_lds16(vs + 24 * 4096, vd + 1536);                                        \
  }

  STAGE(0, half)

  for (int i = 0; i < 16; i++){
    const int buf = i & 1;
    __syncthreads();                         // staging(buf) drained; buf^1 free
    if (i + 1 < 16) STAGE(buf ^ 1, 2 * (i + 1) + half)

    const short* kb_l = Ks  + (half * 2 + buf) * 4096;
    const short* vb_l = Vts + (half * 2 + buf) * 4096;

    // ---- hoist all 8 kf reads (q-independent) ----
    bf16x8 kf[2][4];
#pragma unroll
    for (int s32 = 0; s32 < 2; s32++){
      const int key = s32 * 32 + q5;
#pragma unroll
      for (int c = 0; c < 4; c++)
        kf[s32][c] = *(const bf16x8*)(&kb_l[key * 64 + (((2*c + hh) ^ (key & 7)) << 3)]);
    }

    // ---- S^T = K·Q^T for both q-groups: 4 independent MFMA chains ----
    f32x16 sacc[2][2];   // [qg][s32]
#pragma unroll
    for (int t = 0; t < 16; t++){
      sacc[0][0][t] = 0.f; sacc[0][1][t] = 0.f;
      sacc[1][0][t] = 0.f; sacc[1][1][t] = 0.f;
    }
#pragma unroll
    for (int c = 0; c < 4; c++){
      sacc[0][0] = __builtin_amdgcn_mfma_f32_32x32x16_bf16(kf[0][c], qf[0][c], sacc[0][0], 0, 0, 0);
      sacc[0][1] = __builtin_amdgcn_mfma_f32_32x32x16_bf16(kf[1][c], qf[0][c], sacc[0][1], 0, 0, 0);
      sacc[1][0] = __builtin_amdgcn_mfma_f32_32x32x16_bf16(kf[0][c], qf[1][c], sacc[1][0], 0, 0, 0);
      sacc[1][1] = __builtin_amdgcn_mfma_f32_32x32x16_bf16(kf[1][c], qf[1][c], sacc[1][1], 0, 0, 0);
    }

    // ---- P = exp2(S^T); pack to bf16; l via VALU partial trees ----
    bf16x8 pf[2][2][2];   // [qg][s32][c]
#pragma unroll
    for (int qg = 0; qg < 2; qg++){
#pragma unroll
      for (int s32 = 0; s32 < 2; s32++){
        unsigned int pu[16];
        float pp[4] = {0.f, 0.f, 0.f, 0.f};
#pragma unroll
        for (int t = 0; t < 16; t++){
          const float e = __builtin_amdgcn_exp2f(sacc[qg][s32][t]);
          pp[t & 3] += e;
          unsigned int u; __builtin_memcpy(&u, &e, 4);
          pu[t] = u + 0x8000u;               // round into top 16 bits
        }
        lacc[qg] += (pp[0] + pp[1]) + (pp[2] + pp[3]);
#pragma unroll
        for (int c = 0; c < 2; c++){
          u32x4 tmp;
          tmp[0] = __builtin_amdgcn_perm(pu[4*c + 1], pu[4*c + 0], 0x07060302u);
          tmp[1] = __builtin_amdgcn_perm(pu[4*c + 3], pu[4*c + 2], 0x07060302u);
          tmp[2] = __builtin_amdgcn_perm(pu[8 + 4*c + 1], pu[8 + 4*c + 0], 0x07060302u);
          tmp[3] = __builtin_amdgcn_perm(pu[8 + 4*c + 3], pu[8 + 4*c + 2], 0x07060302u);
          __builtin_memcpy(&pf[qg][s32][c], &tmp, 16);
        }
      }
    }

    // ---- O^T += V^T·P^T : vf read once, consumed by both q-groups ----
#pragma unroll
    for (int s32 = 0; s32 < 2; s32++){
#pragma unroll
      for (int c = 0; c < 2; c++){
#pragma unroll
        for (int mt = 0; mt < 2; mt++){
          const int d = mt * 32 + q5;
          bf16x8 vf = *(const bf16x8*)(&vb_l[d * 64 + (((s32*4 + 2*c + hh) ^ (d & 7)) << 3)]);
          oacc[0][mt] = __builtin_amdgcn_mfma_f32_32x32x16_bf16(vf, pf[0][s32][c], oacc[0][mt], 0, 0, 0);
          oacc[1][mt] = __builtin_amdgcn_mfma_f32_32x32x16_bf16(vf, pf[1][s32][c], oacc[1][mt], 0, 0, 0);
        }
      }
    }
  }

  // ---- combine halves through LDS, then store O[q][d] = O^T / l ----
  const int widx = wg * 64 + lane;           // 0..127
  __syncthreads();                           // all buffer reads done
#pragma unroll
  for (int qg = 0; qg < 2; qg++){
    const float lh = lacc[qg] + __shfl_xor(lacc[qg], 32);
    if (half == 1){
      float* base = scr + widx * 33;
#pragma unroll
      for (int t = 0; t < 16; t++){ base[t] = oacc[qg][0][t]; base[16 + t] = oacc[qg][1][t]; }
      scr[4224 + widx] = lh;
    }
    __syncthreads();
    if (half == 0){
      const float* base = scr + widx * 33;
      const float l2 = scr[4224 + widx];
      const float linv = 1.0f / (lh + l2);
      const size_t orow = ((size_t)b * 2048 + q0 + qg * 32 + q5) * 1024 + (size_t)h * 64;
#pragma unroll
      for (int mt = 0; mt < 2; mt++){
#pragma unroll
        for (int g = 0; g < 4; g++){
          bf16x4 o4;
#pragma unroll
          for (int u = 0; u < 4; u++)
            o4[u] = f2b((oacc[qg][mt][g*4 + u] + base[mt*16 + g*4 + u]) * linv);
          *(bf16x4*)(O + orow + mt*32 + g*8 + 4*hh) = o4;
        }
      }
    }
    __syncthreads();
  }
}
#undef STAGE

// ---------------------------------------------------------------------------
extern "C" void kernel_launch(void* const* d_in, const int* in_sizes, int n_in,
                              void* d_out, int out_size, void* d_ws, size_t ws_size,
                              hipStream_t stream) {
  const float* emb  = (const float*)d_in[0];
  const float* ctx  = (const float*)d_in[1];
  const float* Wq   = (const float*)d_in[2];
  const float* Wk   = (const float*)d_in[3];
  const float* Wv   = (const float*)d_in[4];
  const float* Wu   = (const float*)d_in[5];
  const float* bu   = (const float*)d_in[6];
  const float* qn_w = (const float*)d_in[7];
  const float* qn_b = (const float*)d_in[8];
  const float* kn_w = (const float*)d_in[9];
  const float* kn_b = (const float*)d_in[10];
  float* out = (float*)d_out;

  const size_t BIG = (size_t)4096 * 1024;
  const size_t WSZ = (size_t)1024 * 1024;
  short* ws   = (short*)d_ws;
  short* embh = ws;
  short* ctxh = embh + BIG;
  short* Wqh  = ctxh + BIG;
  short* Wkh  = Wqh + WSZ;
  short* Wvh  = Wkh + WSZ;
  short* Wuh  = Wvh + WSZ;
  short* qh   = Wuh + WSZ;
  short* kh   = qh + BIG;
  short* vth  = kh + BIG;    // V^T [inner][token], key-permuted columns
  short* aoh  = vth + BIG;

  cvt6_kernel<<<12288, 256, 0, stream>>>(emb, ctx, Wq, Wk, Wv, Wu,
                                         embh, ctxh, Wqh, Wkh, Wvh, Wuh);

  gemm_qkv_kernel<<<dim3(256, 3), 256, 0, stream>>>(
      embh, ctxh, Wqh, Wkh, Wvh, qh, kh, vth,
      qn_w, qn_b, kn_w, kn_b);

  flash2_kernel<<<dim3(16, 16, 2), 256, 0, stream>>>(qh, kh, vth, aoh);

  gemm_out_kernel<<<dim3(32, 16), 256, 0, stream>>>(aoh, Wuh, out, bu);
}

// Round 6
// 192.611 us; speedup vs baseline: 1.3188x; 1.0182x over previous
//
#include <hip/hip_runtime.h>

// ============================================================================
// MultiHeadCrossAttention on MI355X (gfx950) — round 14
//   B=2, SQ=SK=2048, H=16, D=64, EMB=CTX=INNER=1024, fp32 in/out.
//
// 4 dispatches:
//   1. cvt6: all fp32->bf16 conversions
//   2. gemm_qkv: 128x128 tiles (m97 shape), XOR-swizzled LDS,
//      q (softmax scale folded), k (+fused LN), vT (key-permuted cols)
//   3. flash2 v6 (r1 best, verbatim): 4-wave blocks, 2-way K-split,
//      64 q-rows per wave, kf/vf shared across 2 q-groups, VALU l-sum
//   4. gemm_out: 64x64 tiles, PAIRED K-staging (2x BK=64 sub-tiles per
//      barrier pair -> 8 barrier pairs instead of 16), 32 KB LDS,
//      1024 blocks = 4/CU preserved
// ============================================================================

typedef __attribute__((ext_vector_type(8)))  short bf16x8;
typedef __attribute__((ext_vector_type(4)))  short bf16x4;
typedef __attribute__((ext_vector_type(4)))  float f32x4;
typedef __attribute__((ext_vector_type(16))) float f32x16;
typedef __attribute__((ext_vector_type(4)))  unsigned int u32x4;

#define SM_SCALE 0.18033688f   // 0.125 * log2(e), folded into q at LN

typedef __attribute__((address_space(1))) const void cg_void;
typedef __attribute__((address_space(3))) void lds_void_t;

__device__ __forceinline__ void gl_lds16(const void* g, void* l){
  __builtin_amdgcn_global_load_lds((cg_void*)g, (lds_void_t*)l, 16, 0, 0);
}

__device__ __forceinline__ short f2b(float f){
  unsigned int u;
  __builtin_memcpy(&u, &f, 4);
  u += 0x7fffu + ((u >> 16) & 1u);   // round-to-nearest-even
  return (short)(u >> 16);
}

// ---------------------------------------------------------------------------
// Fused fp32 -> bf16 convert of all six inputs (12M elems, 4 per thread).
// ---------------------------------------------------------------------------
__global__ __launch_bounds__(256) void cvt6_kernel(
    const float* __restrict__ emb, const float* __restrict__ ctx,
    const float* __restrict__ Wq, const float* __restrict__ Wk,
    const float* __restrict__ Wv, const float* __restrict__ Wu,
    short* __restrict__ o_emb, short* __restrict__ o_ctx,
    short* __restrict__ o_wq, short* __restrict__ o_wk,
    short* __restrict__ o_wv, short* __restrict__ o_wu)
{
  const long M1 = 1024L * 1024L, M4 = 4L * M1;
  long e = ((long)blockIdx.x * 256 + threadIdx.x) * 4;
  if (e >= 12L * M1) return;
  const float* src; short* dst; long off;
  if      (e <     M4)      { src = emb; dst = o_emb; off = e;           }
  else if (e < 2 * M4)      { src = ctx; dst = o_ctx; off = e - M4;      }
  else if (e < 2 * M4 + M1) { src = Wq;  dst = o_wq;  off = e - 2 * M4;  }
  else if (e < 2 * M4 + 2*M1){src = Wk;  dst = o_wk;  off = e - 2*M4 - M1;}
  else if (e < 2 * M4 + 3*M1){src = Wv;  dst = o_wv;  off = e - 2*M4 - 2*M1;}
  else                      { src = Wu;  dst = o_wu;  off = e - 2*M4 - 3*M1;}
  f32x4 v = *(const f32x4*)(src + off);
  bf16x4 o;
  o[0] = f2b(v[0]); o[1] = f2b(v[1]); o[2] = f2b(v[2]); o[3] = f2b(v[3]);
  *(bf16x4*)(dst + off) = o;
}

// ---------------------------------------------------------------------------
// Fused QKV projections. Grid (256, 3); blockIdx.y = task.
//   task 0: q = (emb@Wq^T -> LN)*SM_SCALE   (bm fastest, x&31)
//   task 1: k = ctx@Wk^T + LN               (bm fastest)
//   task 2: vT = Wv@ctx^T, key-permuted cols (bn fastest, x&31)
// 128x128 tile (m97 shape), BK=64, 4 waves in 2x2, each 64x64 (4x4 MFMA
// 16x16x32). Wave N-span = 64 = one head chunk -> LN stays wave-local.
// 32 KB LDS, 768 blocks = 3 blocks/CU = 12 waves/CU.
// ---------------------------------------------------------------------------
__global__ __launch_bounds__(256, 3) void gemm_qkv_kernel(
    const short* __restrict__ embh, const short* __restrict__ ctxh,
    const short* __restrict__ Wqh, const short* __restrict__ Wkh,
    const short* __restrict__ Wvh,
    short* __restrict__ qo, short* __restrict__ ko, short* __restrict__ vto,
    const float* __restrict__ qw, const float* __restrict__ qb,
    const float* __restrict__ kw, const float* __restrict__ kb)
{
  const int K = 1024;
  __shared__ short As[128 * 64];   // 16 KB
  __shared__ short Bs[128 * 64];   // 16 KB
  const int tid  = threadIdx.x;
  const int wave = tid >> 6, lane = tid & 63;
  const int quad = lane >> 4, r16 = lane & 15;
  const int wm = (wave >> 1) * 64, wn = (wave & 1) * 64;

  const int task = blockIdx.y;
  int bn, bm, N;
  const short *A, *B;
  if (task == 2){
    bn = (blockIdx.x & 31) * 128; bm = (blockIdx.x >> 5) * 128; N = 4096;
    A = Wvh; B = ctxh;
  } else {
    bm = (blockIdx.x & 31) * 128; bn = (blockIdx.x >> 5) * 128; N = 1024;
    A = task ? ctxh : embh; B = task ? Wkh : Wqh;
  }

  f32x4 acc[4][4];
#pragma unroll
  for (int i = 0; i < 4; i++)
#pragma unroll
    for (int j = 0; j < 4; j++)
      acc[i][j] = (f32x4){0.f, 0.f, 0.f, 0.f};

  const int sr7 = (lane >> 3) & 7;
  const size_t arow = (size_t)(bm + wave * 8 + (lane >> 3)) * K
                      + (((lane & 7) ^ sr7) * 8);
  const size_t brow = (size_t)(bn + wave * 8 + (lane >> 3)) * K
                      + (((lane & 7) ^ sr7) * 8);
  const int sw = ((quad ^ (r16 & 7)) << 3);

  for (int k0 = 0; k0 < K; k0 += 64){
#pragma unroll
    for (int i = 0; i < 4; i++)
      gl_lds16(A + arow + (size_t)32 * i * K + k0, &As[wave * 512 + i * 2048]);
#pragma unroll
    for (int i = 0; i < 4; i++)
      gl_lds16(B + brow + (size_t)32 * i * K + k0, &Bs[wave * 512 + i * 2048]);
    __syncthreads();
#pragma unroll
    for (int kk = 0; kk < 2; kk++){
      const int off = sw ^ (kk << 5);
      bf16x8 af[4], bq[4];
#pragma unroll
      for (int i = 0; i < 4; i++)
        af[i] = *(const bf16x8*)(&As[(wm + i*16 + r16) * 64 + off]);
#pragma unroll
      for (int j = 0; j < 4; j++)
        bq[j] = *(const bf16x8*)(&Bs[(wn + j*16 + r16) * 64 + off]);
#pragma unroll
      for (int i = 0; i < 4; i++)
#pragma unroll
        for (int j = 0; j < 4; j++)
          acc[i][j] = __builtin_amdgcn_mfma_f32_16x16x32_bf16(af[i], bq[j], acc[i][j], 0, 0, 0);
    }
    __syncthreads();
  }

  if (task < 2){
    short* Ch = task ? ko : qo;
    const float* lw = task ? kw : qw;
    const float* lb = task ? kb : qb;
    const float post = task ? 1.0f : SM_SCALE;   // fold softmax scale into q
    float wv[4], bv[4];
#pragma unroll
    for (int j = 0; j < 4; j++){
      wv[j] = lw[j*16 + r16] * post;
      bv[j] = lb[j*16 + r16] * post;
    }
#pragma unroll
    for (int i = 0; i < 4; i++){
#pragma unroll
      for (int t = 0; t < 4; t++){
        float a[4];
#pragma unroll
        for (int j = 0; j < 4; j++) a[j] = acc[i][j][t];
        float s = a[0] + a[1] + a[2] + a[3];
        s += __shfl_xor(s, 1); s += __shfl_xor(s, 2);
        s += __shfl_xor(s, 4); s += __shfl_xor(s, 8);
        const float mu = s * 0.015625f;
        float d[4], sq = 0.f;
#pragma unroll
        for (int j = 0; j < 4; j++){ d[j] = a[j] - mu; sq += d[j]*d[j]; }
        sq += __shfl_xor(sq, 1); sq += __shfl_xor(sq, 2);
        sq += __shfl_xor(sq, 4); sq += __shfl_xor(sq, 8);
        const float si = rsqrtf(sq * 0.015625f + 1e-5f);
        const size_t row = (size_t)(bm + wm + i*16 + quad*4 + t);
#pragma unroll
        for (int j = 0; j < 4; j++)
          Ch[row * 1024 + (bn + wn + j*16 + r16)] = f2b(d[j] * si * wv[j] + bv[j]);
      }
    }
  } else {
#pragma unroll
    for (int i = 0; i < 4; i++){
#pragma unroll
      for (int j = 0; j < 4; j++){
        // permute token index within its 32-group into PV fragment order
        const int p = (r16 & 3) | ((j & 1) << 2) | (((r16 >> 2) & 1) << 3)
                      | (((r16 >> 3) & 1) << 4);
        const int col = ((bn + wn + j*16 + r16) & ~31) | p;
#pragma unroll
        for (int t = 0; t < 4; t++){
          const size_t row = (size_t)(bm + wm + i*16 + quad*4 + t);
          vto[row * (size_t)N + col] = f2b(acc[i][j][t]);
        }
      }
    }
  }
}

// ---------------------------------------------------------------------------
// out = ao @ Wu^T + bu. M=4096, N=K=1024, fp32 out.
// 64x64 tile, 256 threads, 4 waves 2x2 each 32x32 (2x2 MFMA).
// PAIRED K-staging: both BK=64 sub-tiles of a 128-chunk staged into separate
// LDS buffers before ONE barrier pair -> 8 barrier pairs total (was 16).
// 32 KB LDS, 1024 blocks = 4/CU (128 KB/CU <= 160). XOR-swizzled LDS.
// Grid (64, 16): bm fastest (same-B blocks share XCD).
// ---------------------------------------------------------------------------
__global__ __launch_bounds__(256, 4) void gemm_out_kernel(
    const short* __restrict__ A, const short* __restrict__ B,
    float* __restrict__ Cf, const float* __restrict__ bias)
{
  const int K = 1024, N = 1024;
  __shared__ short As[2][64 * 64];   // 16 KB
  __shared__ short Bs[2][64 * 64];   // 16 KB
  const int tid  = threadIdx.x;
  const int wave = tid >> 6, lane = tid & 63;
  const int quad = lane >> 4, r16 = lane & 15;
  const int wm = (wave >> 1) * 32, wn = (wave & 1) * 32;
  const int bm = blockIdx.x * 64, bn = blockIdx.y * 64;

  f32x4 acc[2][2];
#pragma unroll
  for (int i = 0; i < 2; i++)
#pragma unroll
    for (int j = 0; j < 2; j++)
      acc[i][j] = (f32x4){0.f, 0.f, 0.f, 0.f};

  const int sr7 = (lane >> 3) & 7;
  const size_t arow = (size_t)(bm + wave * 8 + (lane >> 3)) * K
                      + (((lane & 7) ^ sr7) * 8);
  const size_t brow = (size_t)(bn + wave * 8 + (lane >> 3)) * K
                      + (((lane & 7) ^ sr7) * 8);
  const int sw = ((quad ^ (r16 & 7)) << 3);

  for (int k0 = 0; k0 < K; k0 += 128){
#pragma unroll
    for (int p = 0; p < 2; p++){
#pragma unroll
      for (int i = 0; i < 2; i++){
        gl_lds16(A + arow + (size_t)32 * i * K + k0 + p * 64,
                 &As[p][wave * 512 + i * 2048]);
        gl_lds16(B + brow + (size_t)32 * i * K + k0 + p * 64,
                 &Bs[p][wave * 512 + i * 2048]);
      }
    }
    __syncthreads();
#pragma unroll
    for (int p = 0; p < 2; p++){
#pragma unroll
      for (int kk = 0; kk < 2; kk++){
        const int off = sw ^ (kk << 5);
        bf16x8 af[2], bq[2];
#pragma unroll
        for (int i = 0; i < 2; i++)
          af[i] = *(const bf16x8*)(&As[p][(wm + i*16 + r16) * 64 + off]);
#pragma unroll
        for (int j = 0; j < 2; j++)
          bq[j] = *(const bf16x8*)(&Bs[p][(wn + j*16 + r16) * 64 + off]);
#pragma unroll
        for (int i = 0; i < 2; i++)
#pragma unroll
          for (int j = 0; j < 2; j++)
            acc[i][j] = __builtin_amdgcn_mfma_f32_16x16x32_bf16(af[i], bq[j], acc[i][j], 0, 0, 0);
      }
    }
    __syncthreads();
  }

#pragma unroll
  for (int i = 0; i < 2; i++){
#pragma unroll
    for (int j = 0; j < 2; j++){
      const int col = bn + wn + j*16 + r16;
#pragma unroll
      for (int t = 0; t < 4; t++){
        const size_t row = (size_t)(bm + wm + i*16 + quad*4 + t);
        Cf[row * N + col] = acc[i][j][t] + bias[col];
      }
    }
  }
}

// ---------------------------------------------------------------------------
// MFMA flash attention v6 (r1 best, verbatim) — 4 waves, 2-way K-split,
//   64 q-rows per wave. Grid (16 h, 16 qb, 2 b).
//   wave = half*2 + wg; each wg owns 64 q (two 32-row groups qg=0,1).
//   kf/vf LDS fragments are q-independent -> read ONCE, used by both qg.
//   l via VALU partial trees. 2 blocks/CU (64 KB LDS), 8 waves/CU.
// ---------------------------------------------------------------------------
__global__ __launch_bounds__(256, 2) void flash2_kernel(
    const short* __restrict__ Q, const short* __restrict__ K,
    const short* __restrict__ Vt, short* __restrict__ O)
{
  __shared__ __align__(16) long long smem8[8192];   // 64 KB
  short* Ks  = (short*)smem8;        // 4 bufs x 4096 shorts: [half*2+buf]
  short* Vts = Ks + 16384;
  float* scr = (float*)smem8;        // epilogue reuse

  const int tid = threadIdx.x;
  const int wave = tid >> 6, lane = tid & 63;
  const int half = wave >> 1, wg = wave & 1;
  const int hh = lane >> 5, q5 = lane & 31;
  const int h = blockIdx.x, qb = blockIdx.y, b = blockIdx.z;
  const int q0 = qb * 128 + wg * 64;

  const size_t kbase = ((size_t)b * 2048) * 1024 + (size_t)h * 64;
  const size_t vbase = ((size_t)h * 64) * 4096 + (size_t)b * 2048;

  // Q B-frags for both q-groups (pre-scaled by SM_SCALE at LN)
  bf16x8 qf[2][4];
#pragma unroll
  for (int qg = 0; qg < 2; qg++){
    const size_t qrow = ((size_t)b * 2048 + q0 + qg * 32 + q5) * 1024 + (size_t)h * 64;
#pragma unroll
    for (int c = 0; c < 4; c++)
      qf[qg][c] = *(const bf16x8*)(Q + qrow + c * 16 + hh * 8);
  }

  f32x16 oacc[2][2];   // [qg][mt]
#pragma unroll
  for (int t = 0; t < 16; t++){
    oacc[0][0][t] = 0.f; oacc[0][1][t] = 0.f;
    oacc[1][0][t] = 0.f; oacc[1][1][t] = 0.f;
  }
  float lacc[2] = {0.f, 0.f};

  const int srow = lane >> 3;
  const int csrc = ((lane & 7) ^ srow) * 8;
  const int wr0 = wg * 32;

#define STAGE(bufi, kt)                                                         \
  {                                                                             \
    const short* ks = K + kbase + (size_t)((kt) * 64 + wr0 + srow) * 1024 + csrc; \
    const short* vs = Vt + vbase + (size_t)(wr0 + srow) * 4096 + (kt) * 64 + csrc; \
    short* kd = Ks  + (half * 2 + (bufi)) * 4096 + wr0 * 64;                    \
    short* vd = Vts + (half * 2 + (bufi)) * 4096 + wr0 * 64;                    \
    gl_lds16(ks,             kd);                                               \
    gl_lds16(ks +  8 * 1024, kd + 512);                                         \
    gl_lds16(ks + 16 * 1024, kd + 1024);                                        \
    gl_lds16(ks + 24 * 1024, kd + 1536);                                        \
    gl_lds16(vs,             vd);                                               \
    gl_lds16(vs +  8 * 4096, vd + 512);                                         \
    gl_lds16(vs + 16 * 4096, vd + 1024);                                        \
    gl_lds16(vs + 24 * 4096, vd + 1536);                                        \
  }

  STAGE(0, half)

  for (int i = 0; i < 16; i++){
    const int buf = i & 1;
    __syncthreads();                         // staging(buf) drained; buf^1 free
    if (i + 1 < 16) STAGE(buf ^ 1, 2 * (i + 1) + half)

    const short* kb_l = Ks  + (half * 2 + buf) * 4096;
    const short* vb_l = Vts + (half * 2 + buf) * 4096;

    // ---- hoist all 8 kf reads (q-independent) ----
    bf16x8 kf[2][4];
#pragma unroll
    for (int s32 = 0; s32 < 2; s32++){
      const int key = s32 * 32 + q5;
#pragma unroll
      for (int c = 0; c < 4; c++)
        kf[s32][c] = *(const bf16x8*)(&kb_l[key * 64 + (((2*c + hh) ^ (key & 7)) << 3)]);
    }

    // ---- S^T = K·Q^T for both q-groups: 4 independent MFMA chains ----
    f32x16 sacc[2][2];   // [qg][s32]
#pragma unroll
    for (int t = 0; t < 16; t++){
      sacc[0][0][t] = 0.f; sacc[0][1][t] = 0.f;
      sacc[1][0][t] = 0.f; sacc[1][1][t] = 0.f;
    }
#pragma unroll
    for (int c = 0; c < 4; c++){
      sacc[0][0] = __builtin_amdgcn_mfma_f32_32x32x16_bf16(kf[0][c], qf[0][c], sacc[0][0], 0, 0, 0);
      sacc[0][1] = __builtin_amdgcn_mfma_f32_32x32x16_bf16(kf[1][c], qf[0][c], sacc[0][1], 0, 0, 0);
      sacc[1][0] = __builtin_amdgcn_mfma_f32_32x32x16_bf16(kf[0][c], qf[1][c], sacc[1][0], 0, 0, 0);
      sacc[1][1] = __builtin_amdgcn_mfma_f32_32x32x16_bf16(kf[1][c], qf[1][c], sacc[1][1], 0, 0, 0);
    }

    // ---- P = exp2(S^T); pack to bf16; l via VALU partial trees ----
    bf16x8 pf[2][2][2];   // [qg][s32][c]
#pragma unroll
    for (int qg = 0; qg < 2; qg++){
#pragma unroll
      for (int s32 = 0; s32 < 2; s32++){
        unsigned int pu[16];
        float pp[4] = {0.f, 0.f, 0.f, 0.f};
#pragma unroll
        for (int t = 0; t < 16; t++){
          const float e = __builtin_amdgcn_exp2f(sacc[qg][s32][t]);
          pp[t & 3] += e;
          unsigned int u; __builtin_memcpy(&u, &e, 4);
          pu[t] = u + 0x8000u;               // round into top 16 bits
        }
        lacc[qg] += (pp[0] + pp[1]) + (pp[2] + pp[3]);
#pragma unroll
        for (int c = 0; c < 2; c++){
          u32x4 tmp;
          tmp[0] = __builtin_amdgcn_perm(pu[4*c + 1], pu[4*c + 0], 0x07060302u);
          tmp[1] = __builtin_amdgcn_perm(pu[4*c + 3], pu[4*c + 2], 0x07060302u);
          tmp[2] = __builtin_amdgcn_perm(pu[8 + 4*c + 1], pu[8 + 4*c + 0], 0x07060302u);
          tmp[3] = __builtin_amdgcn_perm(pu[8 + 4*c + 3], pu[8 + 4*c + 2], 0x07060302u);
          __builtin_memcpy(&pf[qg][s32][c], &tmp, 16);
        }
      }
    }

    // ---- O^T += V^T·P^T : vf read once, consumed by both q-groups ----
#pragma unroll
    for (int s32 = 0; s32 < 2; s32++){
#pragma unroll
      for (int c = 0; c < 2; c++){
#pragma unroll
        for (int mt = 0; mt < 2; mt++){
          const int d = mt * 32 + q5;
          bf16x8 vf = *(const bf16x8*)(&vb_l[d * 64 + (((s32*4 + 2*c + hh) ^ (d & 7)) << 3)]);
          oacc[0][mt] = __builtin_amdgcn_mfma_f32_32x32x16_bf16(vf, pf[0][s32][c], oacc[0][mt], 0, 0, 0);
          oacc[1][mt] = __builtin_amdgcn_mfma_f32_32x32x16_bf16(vf, pf[1][s32][c], oacc[1][mt], 0, 0, 0);
        }
      }
    }
  }

  // ---- combine halves through LDS, then store O[q][d] = O^T / l ----
  const int widx = wg * 64 + lane;           // 0..127
  __syncthreads();                           // all buffer reads done
#pragma unroll
  for (int qg = 0; qg < 2; qg++){
    const float lh = lacc[qg] + __shfl_xor(lacc[qg], 32);
    if (half == 1){
      float* base = scr + widx * 33;
#pragma unroll
      for (int t = 0; t < 16; t++){ base[t] = oacc[qg][0][t]; base[16 + t] = oacc[qg][1][t]; }
      scr[4224 + widx] = lh;
    }
    __syncthreads();
    if (half == 0){
      const float* base = scr + widx * 33;
      const float l2 = scr[4224 + widx];
      const float linv = 1.0f / (lh + l2);
      const size_t orow = ((size_t)b * 2048 + q0 + qg * 32 + q5) * 1024 + (size_t)h * 64;
#pragma unroll
      for (int mt = 0; mt < 2; mt++){
#pragma unroll
        for (int g = 0; g < 4; g++){
          bf16x4 o4;
#pragma unroll
          for (int u = 0; u < 4; u++)
            o4[u] = f2b((oacc[qg][mt][g*4 + u] + base[mt*16 + g*4 + u]) * linv);
          *(bf16x4*)(O + orow + mt*32 + g*8 + 4*hh) = o4;
        }
      }
    }
    __syncthreads();
  }
}
#undef STAGE

// ---------------------------------------------------------------------------
extern "C" void kernel_launch(void* const* d_in, const int* in_sizes, int n_in,
                              void* d_out, int out_size, void* d_ws, size_t ws_size,
                              hipStream_t stream) {
  const float* emb  = (const float*)d_in[0];
  const float* ctx  = (const float*)d_in[1];
  const float* Wq   = (const float*)d_in[2];
  const float* Wk   = (const float*)d_in[3];
  const float* Wv   = (const float*)d_in[4];
  const float* Wu   = (const float*)d_in[5];
  const float* bu   = (const float*)d_in[6];
  const float* qn_w = (const float*)d_in[7];
  const float* qn_b = (const float*)d_in[8];
  const float* kn_w = (const float*)d_in[9];
  const float* kn_b = (const float*)d_in[10];
  float* out = (float*)d_out;

  const size_t BIG = (size_t)4096 * 1024;
  const size_t WSZ = (size_t)1024 * 1024;
  short* ws   = (short*)d_ws;
  short* embh = ws;
  short* ctxh = embh + BIG;
  short* Wqh  = ctxh + BIG;
  short* Wkh  = Wqh + WSZ;
  short* Wvh  = Wkh + WSZ;
  short* Wuh  = Wvh + WSZ;
  short* qh   = Wuh + WSZ;
  short* kh   = qh + BIG;
  short* vth  = kh + BIG;    // V^T [inner][token], key-permuted columns
  short* aoh  = vth + BIG;

  cvt6_kernel<<<12288, 256, 0, stream>>>(emb, ctx, Wq, Wk, Wv, Wu,
                                         embh, ctxh, Wqh, Wkh, Wvh, Wuh);

  gemm_qkv_kernel<<<dim3(256, 3), 256, 0, stream>>>(
      embh, ctxh, Wqh, Wkh, Wvh, qh, kh, vth,
      qn_w, qn_b, kn_w, kn_b);

  flash2_kernel<<<dim3(16, 16, 2), 256, 0, stream>>>(qh, kh, vth, aoh);

  gemm_out_kernel<<<dim3(64, 16), 256, 0, stream>>>(aoh, Wuh, out, bu);
}

// Round 7
// 187.697 us; speedup vs baseline: 1.3533x; 1.0262x over previous
//
#include <hip/hip_runtime.h>

// ============================================================================
// MultiHeadCrossAttention on MI355X (gfx950) — round 15
//   B=2, SQ=SK=2048, H=16, D=64, EMB=CTX=INNER=1024, fp32 in/out.
//
// 4 dispatches:
//   1. cvt6: all fp32->bf16 conversions
//   2. gemm_qkv: 128x128 tiles, XOR-swizzled LDS; task2 now stores V in
//      flash2's vf-FRAGMENT order [b][h][kt][mt][s32][c][lane][j]
//   3. flash2 v9: v6 core, but V is NOT staged in LDS — each vf is a
//      coalesced 1KB global load from L2 (fragment-ordered), issued at
//      top of iter so S-MFMA+exp2 cover the latency. K-only staging,
//      32 KB LDS, barrier only gates K.
//   4. gemm_out: r1-exact 64x64 tiles (1024 blocks = 4/CU)
// ============================================================================

typedef __attribute__((ext_vector_type(8)))  short bf16x8;
typedef __attribute__((ext_vector_type(4)))  short bf16x4;
typedef __attribute__((ext_vector_type(4)))  float f32x4;
typedef __attribute__((ext_vector_type(16))) float f32x16;
typedef __attribute__((ext_vector_type(4)))  unsigned int u32x4;

#define SM_SCALE 0.18033688f   // 0.125 * log2(e), folded into q at LN

typedef __attribute__((address_space(1))) const void cg_void;
typedef __attribute__((address_space(3))) void lds_void_t;

__device__ __forceinline__ void gl_lds16(const void* g, void* l){
  __builtin_amdgcn_global_load_lds((cg_void*)g, (lds_void_t*)l, 16, 0, 0);
}

__device__ __forceinline__ short f2b(float f){
  unsigned int u;
  __builtin_memcpy(&u, &f, 4);
  u += 0x7fffu + ((u >> 16) & 1u);   // round-to-nearest-even
  return (short)(u >> 16);
}

// ---------------------------------------------------------------------------
// Fused fp32 -> bf16 convert of all six inputs (12M elems, 4 per thread).
// ---------------------------------------------------------------------------
__global__ __launch_bounds__(256) void cvt6_kernel(
    const float* __restrict__ emb, const float* __restrict__ ctx,
    const float* __restrict__ Wq, const float* __restrict__ Wk,
    const float* __restrict__ Wv, const float* __restrict__ Wu,
    short* __restrict__ o_emb, short* __restrict__ o_ctx,
    short* __restrict__ o_wq, short* __restrict__ o_wk,
    short* __restrict__ o_wv, short* __restrict__ o_wu)
{
  const long M1 = 1024L * 1024L, M4 = 4L * M1;
  long e = ((long)blockIdx.x * 256 + threadIdx.x) * 4;
  if (e >= 12L * M1) return;
  const float* src; short* dst; long off;
  if      (e <     M4)      { src = emb; dst = o_emb; off = e;           }
  else if (e < 2 * M4)      { src = ctx; dst = o_ctx; off = e - M4;      }
  else if (e < 2 * M4 + M1) { src = Wq;  dst = o_wq;  off = e - 2 * M4;  }
  else if (e < 2 * M4 + 2*M1){src = Wk;  dst = o_wk;  off = e - 2*M4 - M1;}
  else if (e < 2 * M4 + 3*M1){src = Wv;  dst = o_wv;  off = e - 2*M4 - 2*M1;}
  else                      { src = Wu;  dst = o_wu;  off = e - 2*M4 - 3*M1;}
  f32x4 v = *(const f32x4*)(src + off);
  bf16x4 o;
  o[0] = f2b(v[0]); o[1] = f2b(v[1]); o[2] = f2b(v[2]); o[3] = f2b(v[3]);
  *(bf16x4*)(dst + off) = o;
}

// ---------------------------------------------------------------------------
// Fused QKV projections. Grid (256, 3); blockIdx.y = task.
//   task 0: q = (emb@Wq^T -> LN)*SM_SCALE   (bm fastest, x&31)
//   task 1: k = ctx@Wk^T + LN               (bm fastest)
//   task 2: vT = Wv@ctx^T stored in flash2 vf-fragment order (bn fastest)
// 128x128 tile, BK=64, 4 waves in 2x2, each 64x64 (4x4 MFMA 16x16x32).
// 32 KB LDS, 768 blocks = 3 blocks/CU = 12 waves/CU.
// ---------------------------------------------------------------------------
__global__ __launch_bounds__(256, 3) void gemm_qkv_kernel(
    const short* __restrict__ embh, const short* __restrict__ ctxh,
    const short* __restrict__ Wqh, const short* __restrict__ Wkh,
    const short* __restrict__ Wvh,
    short* __restrict__ qo, short* __restrict__ ko, short* __restrict__ vto,
    const float* __restrict__ qw, const float* __restrict__ qb,
    const float* __restrict__ kw, const float* __restrict__ kb)
{
  const int K = 1024;
  __shared__ short As[128 * 64];   // 16 KB
  __shared__ short Bs[128 * 64];   // 16 KB
  const int tid  = threadIdx.x;
  const int wave = tid >> 6, lane = tid & 63;
  const int quad = lane >> 4, r16 = lane & 15;
  const int wm = (wave >> 1) * 64, wn = (wave & 1) * 64;

  const int task = blockIdx.y;
  int bn, bm;
  const short *A, *B;
  if (task == 2){
    bn = (blockIdx.x & 31) * 128; bm = (blockIdx.x >> 5) * 128;
    A = Wvh; B = ctxh;
  } else {
    bm = (blockIdx.x & 31) * 128; bn = (blockIdx.x >> 5) * 128;
    A = task ? ctxh : embh; B = task ? Wkh : Wqh;
  }

  f32x4 acc[4][4];
#pragma unroll
  for (int i = 0; i < 4; i++)
#pragma unroll
    for (int j = 0; j < 4; j++)
      acc[i][j] = (f32x4){0.f, 0.f, 0.f, 0.f};

  const int sr7 = (lane >> 3) & 7;
  const size_t arow = (size_t)(bm + wave * 8 + (lane >> 3)) * K
                      + (((lane & 7) ^ sr7) * 8);
  const size_t brow = (size_t)(bn + wave * 8 + (lane >> 3)) * K
                      + (((lane & 7) ^ sr7) * 8);
  const int sw = ((quad ^ (r16 & 7)) << 3);

  for (int k0 = 0; k0 < K; k0 += 64){
#pragma unroll
    for (int i = 0; i < 4; i++)
      gl_lds16(A + arow + (size_t)32 * i * K + k0, &As[wave * 512 + i * 2048]);
#pragma unroll
    for (int i = 0; i < 4; i++)
      gl_lds16(B + brow + (size_t)32 * i * K + k0, &Bs[wave * 512 + i * 2048]);
    __syncthreads();
#pragma unroll
    for (int kk = 0; kk < 2; kk++){
      const int off = sw ^ (kk << 5);
      bf16x8 af[4], bq[4];
#pragma unroll
      for (int i = 0; i < 4; i++)
        af[i] = *(const bf16x8*)(&As[(wm + i*16 + r16) * 64 + off]);
#pragma unroll
      for (int j = 0; j < 4; j++)
        bq[j] = *(const bf16x8*)(&Bs[(wn + j*16 + r16) * 64 + off]);
#pragma unroll
      for (int i = 0; i < 4; i++)
#pragma unroll
        for (int j = 0; j < 4; j++)
          acc[i][j] = __builtin_amdgcn_mfma_f32_16x16x32_bf16(af[i], bq[j], acc[i][j], 0, 0, 0);
    }
    __syncthreads();
  }

  if (task < 2){
    short* Ch = task ? ko : qo;
    const float* lw = task ? kw : qw;
    const float* lb = task ? kb : qb;
    const float post = task ? 1.0f : SM_SCALE;   // fold softmax scale into q
    float wv[4], bv[4];
#pragma unroll
    for (int j = 0; j < 4; j++){
      wv[j] = lw[j*16 + r16] * post;
      bv[j] = lb[j*16 + r16] * post;
    }
#pragma unroll
    for (int i = 0; i < 4; i++){
#pragma unroll
      for (int t = 0; t < 4; t++){
        float a[4];
#pragma unroll
        for (int j = 0; j < 4; j++) a[j] = acc[i][j][t];
        float s = a[0] + a[1] + a[2] + a[3];
        s += __shfl_xor(s, 1); s += __shfl_xor(s, 2);
        s += __shfl_xor(s, 4); s += __shfl_xor(s, 8);
        const float mu = s * 0.015625f;
        float d[4], sq = 0.f;
#pragma unroll
        for (int j = 0; j < 4; j++){ d[j] = a[j] - mu; sq += d[j]*d[j]; }
        sq += __shfl_xor(sq, 1); sq += __shfl_xor(sq, 2);
        sq += __shfl_xor(sq, 4); sq += __shfl_xor(sq, 8);
        const float si = rsqrtf(sq * 0.015625f + 1e-5f);
        const size_t row = (size_t)(bm + wm + i*16 + quad*4 + t);
#pragma unroll
        for (int j = 0; j < 4; j++)
          Ch[row * 1024 + (bn + wn + j*16 + r16)] = f2b(d[j] * si * wv[j] + bv[j]);
      }
    }
  } else {
    // Store V^T directly in flash2's vf-fragment layout:
    //   [b][h][kt][mt][s32][c][lane=hh*32+q5][j]  (512-short fragment blocks)
    // True key-within-32 for (c,hh,j): (j>>2)*16 + 8c + 4hh + (j&3)
    // (cross-checked against the previously-proven permutation p).
#pragma unroll
    for (int i = 0; i < 4; i++){
#pragma unroll
      for (int j4 = 0; j4 < 4; j4++){
#pragma unroll
        for (int t = 0; t < 4; t++){
          const int row  = bm + wm + i*16 + quad*4 + t;   // d-row 0..1023
          const int col0 = bn + wn + j4*16 + r16;         // true token 0..4095
          const int bb  = col0 >> 11, tok = col0 & 2047;
          const int hq  = row >> 6,  dd  = row & 63;
          const int mt  = dd >> 5,   q5l = dd & 31;
          const int kt  = tok >> 6,  tk  = tok & 63;
          const int s32 = (tk >> 5) & 1, ks = tk & 31;
          const int hi  = ks >> 4,   r   = ks & 15;
          const int cc  = r >> 3, hh2 = (r >> 2) & 1, jj = (r & 3) + 4*hi;
          const size_t addr = ((size_t)(bb*16 + hq) * 32 + kt) * 4096
                            + (size_t)(((mt*2 + s32)*2 + cc) * 512)
                            + (hh2*32 + q5l) * 8 + jj;
          vto[addr] = f2b(acc[i][j4][t]);
        }
      }
    }
  }
}

// ---------------------------------------------------------------------------
// out = ao @ Wu^T + bu. M=4096, N=K=1024, fp32 out. (r1-exact)
// 64x64 tile, 256 threads, 4 waves 2x2 each 32x32 (2x2 MFMA). 16 KB LDS ->
// grid 1024 blocks = 4 blocks/CU: block-level overlap hides barrier drains.
// XOR-swizzled LDS. Grid (64, 16): bm fastest (same-B blocks share XCD).
// ---------------------------------------------------------------------------
__global__ __launch_bounds__(256, 4) void gemm_out_kernel(
    const short* __restrict__ A, const short* __restrict__ B,
    float* __restrict__ Cf, const float* __restrict__ bias)
{
  const int K = 1024, N = 1024;
  __shared__ short As[64 * 64];   // 8 KB
  __shared__ short Bs[64 * 64];   // 8 KB
  const int tid  = threadIdx.x;
  const int wave = tid >> 6, lane = tid & 63;
  const int quad = lane >> 4, r16 = lane & 15;
  const int wm = (wave >> 1) * 32, wn = (wave & 1) * 32;
  const int bm = blockIdx.x * 64, bn = blockIdx.y * 64;

  f32x4 acc[2][2];
#pragma unroll
  for (int i = 0; i < 2; i++)
#pragma unroll
    for (int j = 0; j < 2; j++)
      acc[i][j] = (f32x4){0.f, 0.f, 0.f, 0.f};

  const int sr7 = (lane >> 3) & 7;
  const size_t arow = (size_t)(bm + wave * 8 + (lane >> 3)) * K
                      + (((lane & 7) ^ sr7) * 8);
  const size_t brow = (size_t)(bn + wave * 8 + (lane >> 3)) * K
                      + (((lane & 7) ^ sr7) * 8);
  const int sw = ((quad ^ (r16 & 7)) << 3);

  for (int k0 = 0; k0 < K; k0 += 64){
#pragma unroll
    for (int i = 0; i < 2; i++){
      gl_lds16(A + arow + (size_t)32 * i * K + k0, &As[wave * 512 + i * 2048]);
      gl_lds16(B + brow + (size_t)32 * i * K + k0, &Bs[wave * 512 + i * 2048]);
    }
    __syncthreads();
#pragma unroll
    for (int kk = 0; kk < 2; kk++){
      const int off = sw ^ (kk << 5);
      bf16x8 af[2], bq[2];
#pragma unroll
      for (int i = 0; i < 2; i++)
        af[i] = *(const bf16x8*)(&As[(wm + i*16 + r16) * 64 + off]);
#pragma unroll
      for (int j = 0; j < 2; j++)
        bq[j] = *(const bf16x8*)(&Bs[(wn + j*16 + r16) * 64 + off]);
#pragma unroll
      for (int i = 0; i < 2; i++)
#pragma unroll
        for (int j = 0; j < 2; j++)
          acc[i][j] = __builtin_amdgcn_mfma_f32_16x16x32_bf16(af[i], bq[j], acc[i][j], 0, 0, 0);
    }
    __syncthreads();
  }

#pragma unroll
  for (int i = 0; i < 2; i++){
#pragma unroll
    for (int j = 0; j < 2; j++){
      const int col = bn + wn + j*16 + r16;
#pragma unroll
      for (int t = 0; t < 4; t++){
        const size_t row = (size_t)(bm + wm + i*16 + quad*4 + t);
        Cf[row * N + col] = acc[i][j][t] + bias[col];
      }
    }
  }
}

// ---------------------------------------------------------------------------
// MFMA flash attention v9 — v6 core, V direct-from-L2 (no V LDS staging).
//   4 waves, 2-way K-split, 64 q-rows per wave. Grid (16 h, 16 qb, 2 b).
//   K double-buffered in 32 KB LDS (barrier gates K only). V fragments
//   loaded as coalesced 1KB global reads in fragment order, issued at top
//   of iter; S-MFMA + exp2 phases cover the L2 latency.
// ---------------------------------------------------------------------------
__global__ __launch_bounds__(256, 2) void flash2_kernel(
    const short* __restrict__ Q, const short* __restrict__ K,
    const short* __restrict__ Vt, short* __restrict__ O)
{
  __shared__ __align__(16) long long smem8[4096];   // 32 KB
  short* Ks = (short*)smem8;         // 4 bufs x 4096 shorts: [half*2+buf]
  float* scr = (float*)smem8;        // epilogue reuse

  const int tid = threadIdx.x;
  const int wave = tid >> 6, lane = tid & 63;
  const int half = wave >> 1, wg = wave & 1;
  const int hh = lane >> 5, q5 = lane & 31;
  const int h = blockIdx.x, qb = blockIdx.y, b = blockIdx.z;
  const int q0 = qb * 128 + wg * 64;

  const size_t kbase = ((size_t)b * 2048) * 1024 + (size_t)h * 64;
  // V fragment space: [b][h][kt][mt][s32][c][lane][j]
  const short* vbh = Vt + ((size_t)(b * 16 + h)) * 131072;

  // Q B-frags for both q-groups (pre-scaled by SM_SCALE at LN)
  bf16x8 qf[2][4];
#pragma unroll
  for (int qg = 0; qg < 2; qg++){
    const size_t qrow = ((size_t)b * 2048 + q0 + qg * 32 + q5) * 1024 + (size_t)h * 64;
#pragma unroll
    for (int c = 0; c < 4; c++)
      qf[qg][c] = *(const bf16x8*)(Q + qrow + c * 16 + hh * 8);
  }

  f32x16 oacc[2][2];   // [qg][mt]
#pragma unroll
  for (int t = 0; t < 16; t++){
    oacc[0][0][t] = 0.f; oacc[0][1][t] = 0.f;
    oacc[1][0][t] = 0.f; oacc[1][1][t] = 0.f;
  }
  float lacc[2] = {0.f, 0.f};

  const int srow = lane >> 3;
  const int csrc = ((lane & 7) ^ srow) * 8;
  const int wr0 = wg * 32;

#define STAGE(bufi, kt)                                                         \
  {                                                                             \
    const short* ks = K + kbase + (size_t)((kt) * 64 + wr0 + srow) * 1024 + csrc; \
    short* kd = Ks + (half * 2 + (bufi)) * 4096 + wr0 * 64;                     \
    gl_lds16(ks,             kd);                                               \
    gl_lds16(ks +  8 * 1024, kd + 512);                                         \
    gl_lds16(ks + 16 * 1024, kd + 1024);                                        \
    gl_lds16(ks + 24 * 1024, kd + 1536);                                        \
  }

  STAGE(0, half)

  for (int i = 0; i < 16; i++){
    const int buf = i & 1;
    __syncthreads();                         // staging(buf) drained; buf^1 free
    if (i + 1 < 16) STAGE(buf ^ 1, 2 * (i + 1) + half)

    const int ktc = 2 * i + half;            // this iter's 64-key tile

    // ---- issue all 8 vf loads now; S+exp2 phases cover L2 latency ----
    bf16x8 vfr[2][2][2];   // [s32][c][mt]
#pragma unroll
    for (int s32 = 0; s32 < 2; s32++)
#pragma unroll
      for (int c = 0; c < 2; c++)
#pragma unroll
        for (int mt = 0; mt < 2; mt++)
          vfr[s32][c][mt] = *(const bf16x8*)(
              vbh + (size_t)ktc * 4096 + (((mt*2 + s32)*2 + c) * 512) + lane * 8);

    const short* kb_l = Ks + (half * 2 + buf) * 4096;

    // ---- hoist all 8 kf reads (q-independent) ----
    bf16x8 kf[2][4];
#pragma unroll
    for (int s32 = 0; s32 < 2; s32++){
      const int key = s32 * 32 + q5;
#pragma unroll
      for (int c = 0; c < 4; c++)
        kf[s32][c] = *(const bf16x8*)(&kb_l[key * 64 + (((2*c + hh) ^ (key & 7)) << 3)]);
    }

    // ---- S^T = K·Q^T for both q-groups: 4 independent MFMA chains ----
    f32x16 sacc[2][2];   // [qg][s32]
#pragma unroll
    for (int t = 0; t < 16; t++){
      sacc[0][0][t] = 0.f; sacc[0][1][t] = 0.f;
      sacc[1][0][t] = 0.f; sacc[1][1][t] = 0.f;
    }
#pragma unroll
    for (int c = 0; c < 4; c++){
      sacc[0][0] = __builtin_amdgcn_mfma_f32_32x32x16_bf16(kf[0][c], qf[0][c], sacc[0][0], 0, 0, 0);
      sacc[0][1] = __builtin_amdgcn_mfma_f32_32x32x16_bf16(kf[1][c], qf[0][c], sacc[0][1], 0, 0, 0);
      sacc[1][0] = __builtin_amdgcn_mfma_f32_32x32x16_bf16(kf[0][c], qf[1][c], sacc[1][0], 0, 0, 0);
      sacc[1][1] = __builtin_amdgcn_mfma_f32_32x32x16_bf16(kf[1][c], qf[1][c], sacc[1][1], 0, 0, 0);
    }

    // ---- P = exp2(S^T); pack to bf16; l via VALU partial trees ----
    bf16x8 pf[2][2][2];   // [qg][s32][c]
#pragma unroll
    for (int qg = 0; qg < 2; qg++){
#pragma unroll
      for (int s32 = 0; s32 < 2; s32++){
        unsigned int pu[16];
        float pp[4] = {0.f, 0.f, 0.f, 0.f};
#pragma unroll
        for (int t = 0; t < 16; t++){
          const float e = __builtin_amdgcn_exp2f(sacc[qg][s32][t]);
          pp[t & 3] += e;
          unsigned int u; __builtin_memcpy(&u, &e, 4);
          pu[t] = u + 0x8000u;               // round into top 16 bits
        }
        lacc[qg] += (pp[0] + pp[1]) + (pp[2] + pp[3]);
#pragma unroll
        for (int c = 0; c < 2; c++){
          u32x4 tmp;
          tmp[0] = __builtin_amdgcn_perm(pu[4*c + 1], pu[4*c + 0], 0x07060302u);
          tmp[1] = __builtin_amdgcn_perm(pu[4*c + 3], pu[4*c + 2], 0x07060302u);
          tmp[2] = __builtin_amdgcn_perm(pu[8 + 4*c + 1], pu[8 + 4*c + 0], 0x07060302u);
          tmp[3] = __builtin_amdgcn_perm(pu[8 + 4*c + 3], pu[8 + 4*c + 2], 0x07060302u);
          __builtin_memcpy(&pf[qg][s32][c], &tmp, 16);
        }
      }
    }

    // ---- O^T += V^T·P^T : vf from registers, both q-groups consume ----
#pragma unroll
    for (int s32 = 0; s32 < 2; s32++){
#pragma unroll
      for (int c = 0; c < 2; c++){
#pragma unroll
        for (int mt = 0; mt < 2; mt++){
          oacc[0][mt] = __builtin_amdgcn_mfma_f32_32x32x16_bf16(vfr[s32][c][mt], pf[0][s32][c], oacc[0][mt], 0, 0, 0);
          oacc[1][mt] = __builtin_amdgcn_mfma_f32_32x32x16_bf16(vfr[s32][c][mt], pf[1][s32][c], oacc[1][mt], 0, 0, 0);
        }
      }
    }
  }

  // ---- combine halves through LDS, then store O[q][d] = O^T / l ----
  const int widx = wg * 64 + lane;           // 0..127
  __syncthreads();                           // all K-buffer reads done
#pragma unroll
  for (int qg = 0; qg < 2; qg++){
    const float lh = lacc[qg] + __shfl_xor(lacc[qg], 32);
    if (half == 1){
      float* base = scr + widx * 33;
#pragma unroll
      for (int t = 0; t < 16; t++){ base[t] = oacc[qg][0][t]; base[16 + t] = oacc[qg][1][t]; }
      scr[4224 + widx] = lh;
    }
    __syncthreads();
    if (half == 0){
      const float* base = scr + widx * 33;
      const float l2 = scr[4224 + widx];
      const float linv = 1.0f / (lh + l2);
      const size_t orow = ((size_t)b * 2048 + q0 + qg * 32 + q5) * 1024 + (size_t)h * 64;
#pragma unroll
      for (int mt = 0; mt < 2; mt++){
#pragma unroll
        for (int g = 0; g < 4; g++){
          bf16x4 o4;
#pragma unroll
          for (int u = 0; u < 4; u++)
            o4[u] = f2b((oacc[qg][mt][g*4 + u] + base[mt*16 + g*4 + u]) * linv);
          *(bf16x4*)(O + orow + mt*32 + g*8 + 4*hh) = o4;
        }
      }
    }
    __syncthreads();
  }
}
#undef STAGE

// ---------------------------------------------------------------------------
extern "C" void kernel_launch(void* const* d_in, const int* in_sizes, int n_in,
                              void* d_out, int out_size, void* d_ws, size_t ws_size,
                              hipStream_t stream) {
  const float* emb  = (const float*)d_in[0];
  const float* ctx  = (const float*)d_in[1];
  const float* Wq   = (const float*)d_in[2];
  const float* Wk   = (const float*)d_in[3];
  const float* Wv   = (const float*)d_in[4];
  const float* Wu   = (const float*)d_in[5];
  const float* bu   = (const float*)d_in[6];
  const float* qn_w = (const float*)d_in[7];
  const float* qn_b = (const float*)d_in[8];
  const float* kn_w = (const float*)d_in[9];
  const float* kn_b = (const float*)d_in[10];
  float* out = (float*)d_out;

  const size_t BIG = (size_t)4096 * 1024;
  const size_t WSZ = (size_t)1024 * 1024;
  short* ws   = (short*)d_ws;
  short* embh = ws;
  short* ctxh = embh + BIG;
  short* Wqh  = ctxh + BIG;
  short* Wkh  = Wqh + WSZ;
  short* Wvh  = Wkh + WSZ;
  short* Wuh  = Wvh + WSZ;
  short* qh   = Wuh + WSZ;
  short* kh   = qh + BIG;
  short* vth  = kh + BIG;    // V in vf-fragment order [b][h][kt][mt][s32][c][lane][j]
  short* aoh  = vth + BIG;

  cvt6_kernel<<<12288, 256, 0, stream>>>(emb, ctx, Wq, Wk, Wv, Wu,
                                         embh, ctxh, Wqh, Wkh, Wvh, Wuh);

  gemm_qkv_kernel<<<dim3(256, 3), 256, 0, stream>>>(
      embh, ctxh, Wqh, Wkh, Wvh, qh, kh, vth,
      qn_w, qn_b, kn_w, kn_b);

  flash2_kernel<<<dim3(16, 16, 2), 256, 0, stream>>>(qh, kh, vth, aoh);

  gemm_out_kernel<<<dim3(64, 16), 256, 0, stream>>>(aoh, Wuh, out, bu);
}